// Round 15
// baseline (144.320 us; speedup 1.0000x reference)
//
#include <hip/hip_runtime.h>
#include <math.h>

// Problem constants (MSDeformMatchV2HeaderAttn)
#define BB 2
#define LQ 1024
#define DM 256
#define NH 8
#define DH 32
#define NL 4
#define HWsp 1024   // 32*32
#define LIN 4096
#define K9 36
#define NGRP (BB * NH * NL * LQ)  // 65536 groups

typedef short bf16x8 __attribute__((ext_vector_type(8)));
typedef float f32x4 __attribute__((ext_vector_type(4)));

// round-to-nearest-even fp32 -> bf16 bits
__device__ __forceinline__ ushort bf16rn(float x) {
  unsigned u = __float_as_uint(x);
  unsigned r = (u + 0x7FFFu + ((u >> 16) & 1u)) >> 16;
  return (ushort)r;
}
__device__ __forceinline__ float bf16tof(ushort h) {
  return __uint_as_float(((unsigned)h) << 16);
}

// ---- screening top-8 insert (value desc; ties arbitrary — recovery is exact)
#define SHIFT_FROM(J)                                                     \
  {                                                                       \
    if (J <= 6) { v7 = v6; i7 = i6; }                                     \
    if (J <= 5) { v6 = v5; i6 = i5; }                                     \
    if (J <= 4) { v5 = v4; i5 = i4; }                                     \
    if (J <= 3) { v4 = v3; i4 = i3; }                                     \
    if (J <= 2) { v3 = v2; i3 = i2; }                                     \
    if (J <= 1) { v2 = v1; i2 = i1; }                                     \
    if (J <= 0) { v1 = v0; i1 = i0; }                                     \
  }
#define INSERT8(val, index)                                               \
  {                                                                       \
    const float v_ = (val);                                               \
    const int ix_ = (index);                                              \
    if (v_ > v7) {                                                        \
      if (v_ > v3) {                                                      \
        if (v_ > v1) {                                                    \
          if (v_ > v0) { SHIFT_FROM(0) v0 = v_; i0 = ix_; }               \
          else { SHIFT_FROM(1) v1 = v_; i1 = ix_; }                       \
        } else {                                                          \
          if (v_ > v2) { SHIFT_FROM(2) v2 = v_; i2 = ix_; }               \
          else { SHIFT_FROM(3) v3 = v_; i3 = ix_; }                       \
        }                                                                 \
      } else {                                                            \
        if (v_ > v5) {                                                    \
          if (v_ > v4) { SHIFT_FROM(4) v4 = v_; i4 = ix_; }               \
          else { SHIFT_FROM(5) v5 = v_; i5 = ix_; }                       \
        } else {                                                          \
          if (v_ > v6) { SHIFT_FROM(6) v6 = v_; i6 = ix_; }               \
          else { v7 = v_; i7 = ix_; }                                     \
        }                                                                 \
      }                                                                   \
    }                                                                     \
  }

// value-only max / compare-exchange (screening merge; ties arbitrary)
#define VMAX(av, ai, bv, bi)                     \
  { if ((bv) > (av)) { (av) = (bv); (ai) = (bi); } }
#define CEXV(av, ai, bv, bi)                     \
  {                                              \
    const bool g_ = (av) >= (bv);                \
    const float tv_ = g_ ? (av) : (bv);          \
    const int ti_ = g_ ? (ai) : (bi);            \
    (bv) = g_ ? (bv) : (av); (bi) = g_ ? (bi) : (ai); \
    (av) = tv_; (ai) = ti_;                      \
  }

#define LEXGT(v_, ix_, vv, ii) (((v_) > (vv)) || ((v_) == (vv) && (ix_) < (ii)))

// lex-aware insert for exact recovery (candidates arrive in arbitrary order)
#define INSERT4LEX(val, index)                                               \
  {                                                                          \
    const float v_ = (val);                                                  \
    const int ix_ = (index);                                                 \
    if (LEXGT(v_, ix_, rv3, ri3)) {                                          \
      if (LEXGT(v_, ix_, rv1, ri1)) {                                        \
        if (LEXGT(v_, ix_, rv0, ri0)) {                                      \
          rv3 = rv2; ri3 = ri2; rv2 = rv1; ri2 = ri1; rv1 = rv0; ri1 = ri0;  \
          rv0 = v_; ri0 = ix_;                                               \
        } else {                                                             \
          rv3 = rv2; ri3 = ri2; rv2 = rv1; ri2 = ri1; rv1 = v_; ri1 = ix_;   \
        }                                                                    \
      } else {                                                               \
        if (LEXGT(v_, ix_, rv2, ri2)) {                                      \
          rv3 = rv2; ri3 = ri2; rv2 = v_; ri2 = ix_;                         \
        } else {                                                             \
          rv3 = v_; ri3 = ix_;                                               \
        }                                                                    \
      }                                                                      \
    }                                                                        \
  }

// a := lexmax(a, b) and lex compare-exchange (final top-4 merge — exact path)
#define LMAX(av, ai, bv, bi)                                        \
  {                                                                 \
    const bool g_ = ((av) > (bv)) || ((av) == (bv) && (ai) < (bi)); \
    if (!g_) { (av) = (bv); (ai) = (bi); }                          \
  }
#define CEX(av, ai, bv, bi)                                         \
  {                                                                 \
    const bool g_ = ((av) > (bv)) || ((av) == (bv) && (ai) < (bi)); \
    const float tv_ = g_ ? (av) : (bv);                             \
    const int ti_ = g_ ? (ai) : (bi);                               \
    (bv) = g_ ? (bv) : (av); (bi) = g_ ? (bi) : (ai);               \
    (av) = tv_; (ai) = ti_;                                         \
  }

// per-plane ushort stride of the presplit buffer
#define PSTRIDE ((size_t)BB * NL * NH * 1024 * 32)  // 2,097,152

// ---------------------------------------------------------------------------
// Kernel 0: one-shot bf16x2 split of value, head-major layout:
// vs[part][n][l][h][row(1024)][32] ushort, part in {hi, lo}.
// ---------------------------------------------------------------------------
__global__ __launch_bounds__(256) void vsplit_kernel(
    const float* __restrict__ value, ushort* __restrict__ vs) {
  const int T = blockIdx.x * 256 + threadIdx.x;  // < 262144
  const int flat = T << 3;
  const int n = flat >> 20;
  const int rem = flat & 0xFFFFF;
  const int lin = rem >> 8;
  const int d0 = rem & 255;
  const int l = lin >> 10, row = lin & 1023;
  const int h = d0 >> 5, dd = d0 & 31;

  const float* src = value + (size_t)flat;
  float xf[8];
  *(float4*)&xf[0] = *(const float4*)src;
  *(float4*)&xf[4] = *(const float4*)(src + 4);

  ushort uh[8], ul[8];
  #pragma unroll
  for (int j = 0; j < 8; ++j) {
    const float x = xf[j];
    const ushort h1 = bf16rn(x);
    uh[j] = h1;
    ul[j] = bf16rn(x - bf16tof(h1));
  }
  const size_t ob = ((((size_t)((n * NL + l) * NH + h)) << 10) + row) * 32 + dd;
  *(bf16x8*)(vs + 0 * PSTRIDE + ob) =
      (bf16x8){(short)uh[0], (short)uh[1], (short)uh[2], (short)uh[3],
               (short)uh[4], (short)uh[5], (short)uh[6], (short)uh[7]};
  *(bf16x8*)(vs + 1 * PSTRIDE + ob) =
      (bf16x8){(short)ul[0], (short)ul[1], (short)ul[2], (short)ul[3],
               (short)ul[4], (short)ul[5], (short)ul[6], (short)ul[7]};
}

// ---------------------------------------------------------------------------
// Kernel 1 (v14): corr screen via bf16x2 3-MFMA + top-8 quad tournament +
// exact fp32 recovery of 32 candidates. Final per-half top-4 is EXACT (same
// output as R12). LDS 2 planes [64][32]; swizzle s^((row>>1)&3) (0 conflicts).
// SPLIT=2: blockIdx.x = qc*2+half, each block scans 512 k (8 64-row chunks).
// Lane L: C col = q = L&15; rows k = 4*quad + reg, quad = (c<<4)+(t<<2)+g.
// Containment: top-8 approx quads hold all true top-4 elements (screen err
// ~1e-4 vs 4th..8th quad-max gap ~0.5 -> P(miss) ~ 0).
// ---------------------------------------------------------------------------
template <int SPLIT, int PRESPLIT>
__global__ __launch_bounds__(256) void corr_topk_kernel(
    const float* __restrict__ query, const float* __restrict__ value,
    const ushort* __restrict__ vs, int* __restrict__ idx_out,
    float4* __restrict__ pval, int4* __restrict__ pidx) {
  __shared__ ushort hiL[64][32];
  __shared__ ushort loL[64][32];

  const int tid = threadIdx.x;
  const int nh = blockIdx.z;  // n*8+h
  const int n = nh >> 3, h = nh & 7;
  const int l = blockIdx.y;
  const int qc = (SPLIT == 2) ? ((int)blockIdx.x >> 1) : (int)blockIdx.x;
  const int half = (SPLIT == 2) ? ((int)blockIdx.x & 1) : 0;
  const int c0 = (SPLIT == 2) ? (half << 3) : 0;  // 64-row chunks
  const int c1 = (SPLIT == 2) ? (c0 + 8) : 16;
  const int w = tid >> 6, L = tid & 63;
  const int qtile = (qc << 2) + w;     // 0..63
  const int r16 = L & 15, g = L >> 4;  // C: col=r16(q), row-group g

  // ---- Q: fp32 slice (for exact recovery) + bf16x2 fragments ----
  float qf[8];
  bf16x8 qhi, qlo;
  {
    const float* qp =
        query + (size_t)(n * LQ + (qtile << 4) + r16) * DM + h * DH + (g << 3);
    *(float4*)&qf[0] = *(const float4*)qp;
    *(float4*)&qf[4] = *(const float4*)(qp + 4);
    ushort uh[8], ul[8];
    #pragma unroll
    for (int j = 0; j < 8; ++j) {
      const float x = qf[j];
      const ushort h1 = bf16rn(x);
      uh[j] = h1;
      ul[j] = bf16rn(x - bf16tof(h1));
    }
    qhi = (bf16x8){(short)uh[0], (short)uh[1], (short)uh[2], (short)uh[3],
                   (short)uh[4], (short)uh[5], (short)uh[6], (short)uh[7]};
    qlo = (bf16x8){(short)ul[0], (short)ul[1], (short)ul[2], (short)ul[3],
                   (short)ul[4], (short)ul[5], (short)ul[6], (short)ul[7]};
  }

  // screening top-8 quad state (sorted desc by approx value)
  float v0 = -INFINITY, v1 = -INFINITY, v2 = -INFINITY, v3 = -INFINITY,
        v4 = -INFINITY, v5 = -INFINITY, v6 = -INFINITY, v7 = -INFINITY;
  int i0 = 0, i1 = 0, i2 = 0, i3 = 0, i4 = 0, i5 = 0, i6 = 0, i7 = 0;

  // staging mapping: thread -> (srow = tid>>2, s = tid&3); swizzled slot
  const int srow = tid >> 2, s = tid & 3;
  const int wslot = (s ^ ((srow >> 1) & 3)) << 3;
  const int rslot = (g ^ ((r16 >> 1) & 3)) << 3;
  const ushort* psbase =
      PRESPLIT ? vs + ((((size_t)((n * NL + l) * NH + h)) << 10)) * 32 : nullptr;
  const float* vbase = value + (size_t)(n * LIN + l * HWsp) * DM + h * DH;

  for (int c = c0; c < c1; ++c) {
    if (PRESPLIT) {
      const size_t off = ((size_t)((c << 6) + srow)) * 32 + (s << 3);
      *(bf16x8*)&hiL[srow][wslot] = *(const bf16x8*)(psbase + off);
      *(bf16x8*)&loL[srow][wslot] = *(const bf16x8*)(psbase + PSTRIDE + off);
    } else {
      const float* vp = vbase + (size_t)((c << 6) + srow) * DM + (s << 3);
      float xf[8];
      *(float4*)&xf[0] = *(const float4*)vp;
      *(float4*)&xf[4] = *(const float4*)(vp + 4);
      ushort uh[8], ul[8];
      #pragma unroll
      for (int j = 0; j < 8; ++j) {
        const float x = xf[j];
        const ushort h1 = bf16rn(x);
        uh[j] = h1;
        ul[j] = bf16rn(x - bf16tof(h1));
      }
      *(bf16x8*)&hiL[srow][wslot] =
          (bf16x8){(short)uh[0], (short)uh[1], (short)uh[2], (short)uh[3],
                   (short)uh[4], (short)uh[5], (short)uh[6], (short)uh[7]};
      *(bf16x8*)&loL[srow][wslot] =
          (bf16x8){(short)ul[0], (short)ul[1], (short)ul[2], (short)ul[3],
                   (short)ul[4], (short)ul[5], (short)ul[6], (short)ul[7]};
    }
    __syncthreads();

    #pragma unroll
    for (int t = 0; t < 4; ++t) {
      const int row = (t << 4) + r16;
      const bf16x8 ahi = *(const bf16x8*)&hiL[row][rslot];
      const bf16x8 alo = *(const bf16x8*)&loL[row][rslot];
      f32x4 acc = {0.f, 0.f, 0.f, 0.f};
      // bf16x2 screen: 3 terms, smallest-first
      acc = __builtin_amdgcn_mfma_f32_16x16x32_bf16(alo, qhi, acc, 0, 0, 0);
      acc = __builtin_amdgcn_mfma_f32_16x16x32_bf16(ahi, qlo, acc, 0, 0, 0);
      acc = __builtin_amdgcn_mfma_f32_16x16x32_bf16(ahi, qhi, acc, 0, 0, 0);
      const float qm = fmaxf(fmaxf(acc[0], acc[1]), fmaxf(acc[2], acc[3]));
      const int qd = (c << 4) + (t << 2) + g;  // quad id = k/4
      INSERT8(qm, qd);
    }
    __syncthreads();
  }

  // ---- merge top-8 quad lists across the 4 row-groups (lanes 16/32) ----
  #pragma unroll
  for (int m = 16; m < 64; m <<= 1) {
    const float b0 = __shfl_xor(v0, m), b1 = __shfl_xor(v1, m);
    const float b2 = __shfl_xor(v2, m), b3 = __shfl_xor(v3, m);
    const float b4 = __shfl_xor(v4, m), b5 = __shfl_xor(v5, m);
    const float b6 = __shfl_xor(v6, m), b7 = __shfl_xor(v7, m);
    const int j0 = __shfl_xor(i0, m), j1 = __shfl_xor(i1, m);
    const int j2 = __shfl_xor(i2, m), j3 = __shfl_xor(i3, m);
    const int j4 = __shfl_xor(i4, m), j5 = __shfl_xor(i5, m);
    const int j6 = __shfl_xor(i6, m), j7 = __shfl_xor(i7, m);
    // L_i = max(a_i, b_{7-i}) -> bitonic, contains union top-8
    VMAX(v0, i0, b7, j7); VMAX(v1, i1, b6, j6);
    VMAX(v2, i2, b5, j5); VMAX(v3, i3, b4, j4);
    VMAX(v4, i4, b3, j3); VMAX(v5, i5, b2, j2);
    VMAX(v6, i6, b1, j1); VMAX(v7, i7, b0, j0);
    // bitonic cleanup sort8 desc
    CEXV(v0, i0, v4, i4); CEXV(v1, i1, v5, i5);
    CEXV(v2, i2, v6, i6); CEXV(v3, i3, v7, i7);
    CEXV(v0, i0, v2, i2); CEXV(v1, i1, v3, i3);
    CEXV(v4, i4, v6, i6); CEXV(v5, i5, v7, i7);
    CEXV(v0, i0, v1, i1); CEXV(v2, i2, v3, i3);
    CEXV(v4, i4, v5, i5); CEXV(v6, i6, v7, i7);
  }

  // ---- exact recovery: 8 quads x 4 k = 32 candidates, fp32 dots ----
  float rv0 = -INFINITY, rv1 = -INFINITY, rv2 = -INFINITY, rv3 = -INFINITY;
  int ri0 = 0, ri1 = 0, ri2 = 0, ri3 = 0;
  #define RECOVER_QUAD(QID)                                              \
    {                                                                    \
      _Pragma("unroll")                                                  \
      for (int j = 0; j < 4; ++j) {                                      \
        const int k = ((QID) << 2) + j;                                  \
        const float* vf = vbase + (size_t)k * DM + (g << 3);             \
        const float4 a0 = *(const float4*)vf;                            \
        const float4 a1 = *(const float4*)(vf + 4);                      \
        float p = qf[0] * a0.x;                                          \
        p = fmaf(qf[1], a0.y, p);                                        \
        p = fmaf(qf[2], a0.z, p);                                        \
        p = fmaf(qf[3], a0.w, p);                                        \
        p = fmaf(qf[4], a1.x, p);                                        \
        p = fmaf(qf[5], a1.y, p);                                        \
        p = fmaf(qf[6], a1.z, p);                                        \
        p = fmaf(qf[7], a1.w, p);                                        \
        p += __shfl_xor(p, 16);                                          \
        p += __shfl_xor(p, 32);                                          \
        INSERT4LEX(p, k);                                                \
      }                                                                  \
    }
  RECOVER_QUAD(i0)
  RECOVER_QUAD(i1)
  RECOVER_QUAD(i2)
  RECOVER_QUAD(i3)
  RECOVER_QUAD(i4)
  RECOVER_QUAD(i5)
  RECOVER_QUAD(i6)
  RECOVER_QUAD(i7)
  #undef RECOVER_QUAD

  if (L < 16) {
    const int q = (qtile << 4) + L;
    const size_t gi = (((size_t)nh * NL + l) << 10) + q;
    if (SPLIT == 2) {
      pval[gi * 2 + half] = make_float4(rv0, rv1, rv2, rv3);
      pidx[gi * 2 + half] = make_int4(ri0, ri1, ri2, ri3);
    } else {
      ((int4*)idx_out)[gi] = make_int4(ri0, ri1, ri2, ri3);
    }
  }
}

// ---------------------------------------------------------------------------
// Kernel 1b: merge the two k-half partial top-4 lists per group AND write the
// loc output directly (exact lex merge, validated R4-R13).
// ---------------------------------------------------------------------------
__global__ __launch_bounds__(256) void merge_topk_loc_kernel(
    const float4* __restrict__ pval, const int4* __restrict__ pidx,
    int* __restrict__ idx_out, float* __restrict__ loc) {
  const int t = blockIdx.x * 256 + threadIdx.x;  // < NGRP
  const float4 av = pval[t * 2 + 0];
  const int4 ai = pidx[t * 2 + 0];
  const float4 bv = pval[t * 2 + 1];
  const int4 bi = pidx[t * 2 + 1];
  float w0 = av.x, w1 = av.y, w2 = av.z, w3 = av.w;
  int m0 = ai.x, m1 = ai.y, m2 = ai.z, m3 = ai.w;
  LMAX(w0, m0, bv.w, bi.w);
  LMAX(w1, m1, bv.z, bi.z);
  LMAX(w2, m2, bv.y, bi.y);
  LMAX(w3, m3, bv.x, bi.x);
  CEX(w0, m0, w2, m2);
  CEX(w1, m1, w3, m3);
  CEX(w0, m0, w1, m1);
  CEX(w2, m2, w3, m3);
  ((int4*)idx_out)[t] = make_int4(m0, m1, m2, m3);

  // decode group: gi = ((n*8+h)*4+l)*1024 + q
  const int q = t & 1023, l = (t >> 10) & 3, h = (t >> 12) & 7, n = t >> 15;
  // loc float2 base: (((n*1024+q)*8+h)*4+l)*36
  const size_t base2 =
      (size_t)((((((n << 10) + q) << 3) + h) << 2) + l) * 36;
  float4* lp4 = (float4*)(loc + base2 * 2);  // 288B per thread, 16B-aligned
  const int idxs[4] = {m0, m1, m2, m3};
  #pragma unroll
  for (int dd = 0; dd < 9; ++dd) {
    const int delta = (dd / 3 - 1) * 32 + (dd % 3) - 1;
    float vv[8];
    #pragma unroll
    for (int p = 0; p < 4; ++p) {
      int res = idxs[p] + delta;
      res = min(max(res, 0), 961);
      vv[p * 2] = (float)(res >> 5) * 0.03125f;
      vv[p * 2 + 1] = (float)(res & 31) * 0.03125f;
    }
    lp4[dd * 2] = make_float4(vv[0], vv[1], vv[2], vv[3]);
    lp4[dd * 2 + 1] = make_float4(vv[4], vv[5], vv[6], vv[7]);
  }
}

// ---------------------------------------------------------------------------
// Kernel 2 (tier-3 fallback only): standalone loc from idx_buf.
// ---------------------------------------------------------------------------
__global__ __launch_bounds__(256) void loc_kernel(const int* __restrict__ idx_buf,
                                                  float* __restrict__ loc) {
  const int t = blockIdx.x * 256 + threadIdx.x;  // < 2359296
  const int k = t % 36;
  int rest = t / 36;
  const int l = rest & 3; rest >>= 2;
  const int h = rest & 7; rest >>= 3;
  const int q = rest & 1023;
  const int n = rest >> 10;
  const int p = k & 3, dd = k >> 2;  // delta-major: k = dd*4 + p
  const int idx = idx_buf[(((((n << 3) + h) * NL + l) << 10) + q) * 4 + p];
  const int delta = ((dd / 3) - 1) * 32 + (dd % 3) - 1;
  int res = idx + delta;
  res = min(max(res, 0), 961);
  const int W = res >> 5, H = res & 31;
  ((float2*)loc)[t] = make_float2((float)W * 0.03125f, (float)H * 0.03125f);
}

// ---------------------------------------------------------------------------
// Kernel 3: gather+average, wave-per-(n,q,h,l) (R7-R13-validated).
// ---------------------------------------------------------------------------
__global__ __launch_bounds__(256) void gather_kernel(
    const float* __restrict__ value, const int* __restrict__ idx_buf,
    float* __restrict__ acc_out) {
  __shared__ float4 red[NL][8];
  const int bh = blockIdx.x;  // (n*1024+q)*8 + h
  const int h = bh & 7;
  const int nq = bh >> 3;
  const int n = nq >> 10, q = nq & 1023;
  const int tid = threadIdx.x;
  const int l = tid >> 6;  // wave = level
  const int L = tid & 63;
  const int cp = L >> 3, d4 = L & 7;

  const int4 id4 =
      ((const int4*)idx_buf)[((((size_t)((n << 3) + h)) * NL + l) << 10) + q];
  const float4* vb4 =
      (const float4*)(value + (size_t)(n * LIN + l * HWsp) * DM + h * DH) + d4;

  float4 a = make_float4(0.f, 0.f, 0.f, 0.f);
  #pragma unroll
  for (int p = 0; p < 4; ++p) {
    const int idx = (p == 0) ? id4.x : (p == 1) ? id4.y : (p == 2) ? id4.z : id4.w;
    const int H0 = idx & 31, W0 = idx >> 5;
    if (H0 >= 2 && H0 <= 30 && W0 >= 2 && W0 <= 28) {
      const int idxT = (H0 << 5) + W0;
      const int c0i = cp << 1;
      const int ax0 = c0i & 3, ay = c0i >> 2;
      const int r0 = idxT + (ax0 - 2) * 32 + (ay - 2);
      const float wy = (ay == 1 || ay == 2) ? 2.f : 1.f;
      const float f0 = ((ax0 == 2) ? 2.f : 1.f) * wy;
      const float f1 = ((ax0 + 1 == 1) ? 2.f : 1.f) * wy;
      const float4 va = vb4[(size_t)r0 * 64];
      const float4 vbb = vb4[(size_t)(r0 + 32) * 64];
      a.x += f0 * va.x + f1 * vbb.x;
      a.y += f0 * va.y + f1 * vbb.y;
      a.z += f0 * va.z + f1 * vbb.z;
      a.w += f0 * va.w + f1 * vbb.w;
    } else {
      #pragma unroll
      for (int it = 0; it < 5; ++it) {
        const int u = cp + (it << 3);
        const int cell = u >> 2, corner = u & 3;
        const int dy = (cell >= 3) + (cell >= 6) - 1;
        const int dx = cell - (dy + 1) * 3 - 1;
        int res = idx + dy * 32 + dx;
        res = min(max(res, 0), 961);
        const int W = res >> 5, H = res & 31;
        const int cw = corner & 1, ch = corner >> 1;
        const bool ok = (u < 36) && (W >= cw) && (H >= ch);
        const int row = ok ? (((H - ch) << 5) + (W - cw)) : 0;
        const float wgt = ok ? 1.f : 0.f;
        const float4 v = vb4[(size_t)row * 64];
        a.x += wgt * v.x;
        a.y += wgt * v.y;
        a.z += wgt * v.z;
        a.w += wgt * v.w;
      }
    }
  }

  #pragma unroll
  for (int m = 8; m < 64; m <<= 1) {
    a.x += __shfl_xor(a.x, m);
    a.y += __shfl_xor(a.y, m);
    a.z += __shfl_xor(a.z, m);
    a.w += __shfl_xor(a.w, m);
  }
  if (L < 8) red[l][L] = a;
  __syncthreads();
  if (tid < 8) {
    const float4 s0 = red[0][tid], s1 = red[1][tid], s2 = red[2][tid],
                 s3 = red[3][tid];
    float4 o;
    o.x = (s0.x + s1.x + s2.x + s3.x) * (1.0f / 576.0f);
    o.y = (s0.y + s1.y + s2.y + s3.y) * (1.0f / 576.0f);
    o.z = (s0.z + s1.z + s2.z + s3.z) * (1.0f / 576.0f);
    o.w = (s0.w + s1.w + s2.w + s3.w) * (1.0f / 576.0f);
    ((float4*)(acc_out + (size_t)nq * DM + h * DH))[tid] = o;
  }
}

// ---------------------------------------------------------------------------
// Kernel 4: out = acc @ W^T + b.  256 blocks x 256 threads, 8 q-rows/block.
// ---------------------------------------------------------------------------
__global__ __launch_bounds__(256) void proj_kernel(
    const float* __restrict__ acc_in, const float* __restrict__ W,
    const float* __restrict__ bias, float* __restrict__ out) {
  __shared__ float la[8][256];
  const int qb = blockIdx.x << 3;
  const int tid = threadIdx.x;
  for (int i = tid; i < 8 * 256; i += 256)
    la[i >> 8][i & 255] = acc_in[((size_t)qb << 8) + i];
  __syncthreads();
  const float* wrow = W + (size_t)tid * 256;
  float s0 = 0.f, s1 = 0.f, s2 = 0.f, s3 = 0.f, s4 = 0.f, s5 = 0.f, s6 = 0.f, s7 = 0.f;
  for (int c0 = 0; c0 < 256; c0 += 4) {
    const float4 wv = *(const float4*)(wrow + c0);
    #define PROJ_STEP(qi, sreg)                                   \
      {                                                           \
        const float4 av = *(const float4*)&la[qi][c0];            \
        sreg = fmaf(wv.x, av.x, sreg);                            \
        sreg = fmaf(wv.y, av.y, sreg);                            \
        sreg = fmaf(wv.z, av.z, sreg);                            \
        sreg = fmaf(wv.w, av.w, sreg);                            \
      }
    PROJ_STEP(0, s0) PROJ_STEP(1, s1) PROJ_STEP(2, s2) PROJ_STEP(3, s3)
    PROJ_STEP(4, s4) PROJ_STEP(5, s5) PROJ_STEP(6, s6) PROJ_STEP(7, s7)
    #undef PROJ_STEP
  }
  const float bj = bias[tid];
  out[(size_t)(qb + 0) * 256 + tid] = s0 + bj;
  out[(size_t)(qb + 1) * 256 + tid] = s1 + bj;
  out[(size_t)(qb + 2) * 256 + tid] = s2 + bj;
  out[(size_t)(qb + 3) * 256 + tid] = s3 + bj;
  out[(size_t)(qb + 4) * 256 + tid] = s4 + bj;
  out[(size_t)(qb + 5) * 256 + tid] = s5 + bj;
  out[(size_t)(qb + 6) * 256 + tid] = s6 + bj;
  out[(size_t)(qb + 7) * 256 + tid] = s7 + bj;
}

// ---------------------------------------------------------------------------
extern "C" void kernel_launch(void* const* d_in, const int* in_sizes, int n_in,
                              void* d_out, int out_size, void* d_ws, size_t ws_size,
                              hipStream_t stream) {
  (void)in_sizes; (void)n_in; (void)out_size;
  const float* query = (const float*)d_in[0];
  const float* value = (const float*)d_in[2];
  const float* opw = (const float*)d_in[5];
  const float* opb = (const float*)d_in[6];

  float* out = (float*)d_out;               // [2,1024,256]
  float* loc = out + (size_t)BB * LQ * DM;  // [2,1024,8,4,36,2]

  const size_t SPLITB = 2 * PSTRIDE * sizeof(ushort);        // 8.39 MB
  const size_t PARTB = (size_t)NGRP * 2 * 16;                // 2 MB each
  const size_t IDXB = (size_t)NGRP * 4 * sizeof(int);        // 1 MB
  const size_t ACCB = (size_t)BB * LQ * DM * sizeof(float);  // 2 MB

  if (ws_size >= SPLITB + 2 * PARTB + IDXB + ACCB) {
    // tier 1: presplit (2 planes) + k-split x2; merge+loc fused
    ushort* vsb = (ushort*)d_ws;
    float4* pval = (float4*)((char*)d_ws + SPLITB);
    int4* pidx = (int4*)((char*)d_ws + SPLITB + PARTB);
    int* idx_buf = (int*)((char*)d_ws + SPLITB + 2 * PARTB);
    float* acc_buf = (float*)((char*)d_ws + SPLITB + 2 * PARTB + IDXB);

    vsplit_kernel<<<dim3(1024), 256, 0, stream>>>(value, vsb);
    corr_topk_kernel<2, 1><<<dim3(32, NL, BB * NH), 256, 0, stream>>>(
        query, value, vsb, idx_buf, pval, pidx);
    merge_topk_loc_kernel<<<dim3(NGRP / 256), 256, 0, stream>>>(pval, pidx,
                                                                idx_buf, loc);
    gather_kernel<<<dim3(BB * LQ * NH), 256, 0, stream>>>(value, idx_buf, acc_buf);
    proj_kernel<<<dim3(BB * LQ / 8), 256, 0, stream>>>(acc_buf, opw, opb, out);
  } else if (ws_size >= 2 * PARTB + IDXB + ACCB) {
    // tier 2: in-kernel bf16x2 conversion + k-split x2; merge+loc fused
    float4* pval = (float4*)d_ws;
    int4* pidx = (int4*)((char*)d_ws + PARTB);
    int* idx_buf = (int*)((char*)d_ws + 2 * PARTB);
    float* acc_buf = (float*)((char*)d_ws + 2 * PARTB + IDXB);

    corr_topk_kernel<2, 0><<<dim3(32, NL, BB * NH), 256, 0, stream>>>(
        query, value, (const ushort*)nullptr, idx_buf, pval, pidx);
    merge_topk_loc_kernel<<<dim3(NGRP / 256), 256, 0, stream>>>(pval, pidx,
                                                                idx_buf, loc);
    gather_kernel<<<dim3(BB * LQ * NH), 256, 0, stream>>>(value, idx_buf, acc_buf);
    proj_kernel<<<dim3(BB * LQ / 8), 256, 0, stream>>>(acc_buf, opw, opb, out);
  } else {
    // tier 3: minimal workspace, single-pass + standalone loc
    int* idx_buf = (int*)d_ws;
    float* acc_buf = (float*)((char*)d_ws + IDXB);

    corr_topk_kernel<1, 0><<<dim3(16, NL, BB * NH), 256, 0, stream>>>(
        query, value, (const ushort*)nullptr, idx_buf, (float4*)nullptr,
        (int4*)nullptr);
    loc_kernel<<<dim3((BB * LQ * NH * NL * K9) / 256), 256, 0, stream>>>(idx_buf, loc);
    gather_kernel<<<dim3(BB * LQ * NH), 256, 0, stream>>>(value, idx_buf, acc_buf);
    proj_kernel<<<dim3(BB * LQ / 8), 256, 0, stream>>>(acc_buf, opw, opb, out);
  }
}

// Round 16
// 105.274 us; speedup vs baseline: 1.3709x; 1.3709x over previous
//
#include <hip/hip_runtime.h>
#include <math.h>

// Problem constants (MSDeformMatchV2HeaderAttn)
#define BB 2
#define LQ 1024
#define DM 256
#define NH 8
#define DH 32
#define NL 4
#define HWsp 1024   // 32*32
#define LIN 4096
#define K9 36
#define NGRP (BB * NH * NL * LQ)  // 65536 groups

typedef short bf16x8 __attribute__((ext_vector_type(8)));
typedef float f32x4 __attribute__((ext_vector_type(4)));

// round-to-nearest-even fp32 -> bf16 bits
__device__ __forceinline__ ushort bf16rn(float x) {
  unsigned u = __float_as_uint(x);
  unsigned r = (u + 0x7FFFu + ((u >> 16) & 1u)) >> 16;
  return (ushort)r;
}
__device__ __forceinline__ float bf16tof(ushort h) {
  return __uint_as_float(((unsigned)h) << 16);
}

// stable insert of one (val,id) into sorted-desc 4-list (strict >; ascending
// id scan order => lower id wins ties)
#define INSERT4(val, index)                                              \
  {                                                                      \
    const float v_ = (val);                                              \
    const int ix_ = (index);                                             \
    if (v_ > v3) {                                                       \
      if (v_ > v1) {                                                     \
        if (v_ > v0) {                                                   \
          v3 = v2; i3 = i2; v2 = v1; i2 = i1; v1 = v0; i1 = i0;          \
          v0 = v_; i0 = ix_;                                             \
        } else {                                                         \
          v3 = v2; i3 = i2; v2 = v1; i2 = i1; v1 = v_; i1 = ix_;         \
        }                                                                \
      } else {                                                           \
        if (v_ > v2) {                                                   \
          v3 = v2; i3 = i2; v2 = v_; i2 = ix_;                           \
        } else {                                                         \
          v3 = v_; i3 = ix_;                                             \
        }                                                                \
      }                                                                  \
    }                                                                    \
  }

// a := lexmax(a, b)  under (value desc, index asc)
#define LMAX(av, ai, bv, bi)                                        \
  {                                                                 \
    const bool g_ = ((av) > (bv)) || ((av) == (bv) && (ai) < (bi)); \
    if (!g_) { (av) = (bv); (ai) = (bi); }                          \
  }
// compare-exchange: order (a,b) so a >=lex b
#define CEX(av, ai, bv, bi)                                         \
  {                                                                 \
    const bool g_ = ((av) > (bv)) || ((av) == (bv) && (ai) < (bi)); \
    const float tv_ = g_ ? (av) : (bv);                             \
    const int ti_ = g_ ? (ai) : (bi);                               \
    (bv) = g_ ? (bv) : (av); (bi) = g_ ? (bi) : (ai);               \
    (av) = tv_; (ai) = ti_;                                         \
  }

// per-plane ushort stride of the presplit buffer
#define PSTRIDE ((size_t)BB * NL * NH * 1024 * 32)  // 2,097,152

// ---------------------------------------------------------------------------
// Kernel 0: one-shot bf16x3 split of value, head-major layout:
// vs[part][n][l][h][row(1024)][32] ushort.
// ---------------------------------------------------------------------------
__global__ __launch_bounds__(256) void vsplit_kernel(
    const float* __restrict__ value, ushort* __restrict__ vs) {
  const int T = blockIdx.x * 256 + threadIdx.x;  // < 262144
  const int flat = T << 3;
  const int n = flat >> 20;
  const int rem = flat & 0xFFFFF;
  const int lin = rem >> 8;
  const int d0 = rem & 255;
  const int l = lin >> 10, row = lin & 1023;
  const int h = d0 >> 5, dd = d0 & 31;

  const float* src = value + (size_t)flat;
  float xf[8];
  *(float4*)&xf[0] = *(const float4*)src;
  *(float4*)&xf[4] = *(const float4*)(src + 4);

  ushort uh[8], ul[8], ul2[8];
  #pragma unroll
  for (int j = 0; j < 8; ++j) {
    const float x = xf[j];
    const ushort h1 = bf16rn(x);
    const float r1 = x - bf16tof(h1);
    const ushort h2 = bf16rn(r1);
    const float r2 = r1 - bf16tof(h2);
    uh[j] = h1; ul[j] = h2; ul2[j] = bf16rn(r2);
  }
  const size_t ob = ((((size_t)((n * NL + l) * NH + h)) << 10) + row) * 32 + dd;
  *(bf16x8*)(vs + 0 * PSTRIDE + ob) =
      (bf16x8){(short)uh[0], (short)uh[1], (short)uh[2], (short)uh[3],
               (short)uh[4], (short)uh[5], (short)uh[6], (short)uh[7]};
  *(bf16x8*)(vs + 1 * PSTRIDE + ob) =
      (bf16x8){(short)ul[0], (short)ul[1], (short)ul[2], (short)ul[3],
               (short)ul[4], (short)ul[5], (short)ul[6], (short)ul[7]};
  *(bf16x8*)(vs + 2 * PSTRIDE + ob) =
      (bf16x8){(short)ul2[0], (short)ul2[1], (short)ul2[2], (short)ul2[3],
               (short)ul2[4], (short)ul2[5], (short)ul2[6], (short)ul2[7]};
}

// ---------------------------------------------------------------------------
// Kernel 1 (v12, measured best): corr + stable element top-4 via bf16x3 MFMA.
// LDS [64][32] ushort rows; slot swizzle s ^ ((row>>1)&3) (0 bank conflicts).
// PRESPLIT=1: stage pre-split planes (pure copy). PRESPLIT=0: convert
// in-kernel. SPLIT=2: blockIdx.x = qc*2+half, each block scans 512 k (8
// 64-row chunks), writes partial sorted (val,idx) lists; merge combines.
// Lane L: C col = q = L&15; rows k = base + (L>>4)*4 + reg.
// ---------------------------------------------------------------------------
template <int SPLIT, int PRESPLIT>
__global__ __launch_bounds__(256) void corr_topk_kernel(
    const float* __restrict__ query, const float* __restrict__ value,
    const ushort* __restrict__ vs, int* __restrict__ idx_out,
    float4* __restrict__ pval, int4* __restrict__ pidx) {
  __shared__ ushort hiL[64][32];
  __shared__ ushort loL[64][32];
  __shared__ ushort lo2L[64][32];

  const int tid = threadIdx.x;
  const int nh = blockIdx.z;  // n*8+h
  const int n = nh >> 3, h = nh & 7;
  const int l = blockIdx.y;
  const int qc = (SPLIT == 2) ? ((int)blockIdx.x >> 1) : (int)blockIdx.x;
  const int half = (SPLIT == 2) ? ((int)blockIdx.x & 1) : 0;
  const int c0 = (SPLIT == 2) ? (half << 3) : 0;  // 64-row chunks
  const int c1 = (SPLIT == 2) ? (c0 + 8) : 16;
  const int w = tid >> 6, L = tid & 63;
  const int qtile = (qc << 2) + w;     // 0..63
  const int r16 = L & 15, g = L >> 4;  // C: col=r16(q), row-group g

  // ---- Q: bf16x3 fragments (persistent) ----
  bf16x8 qhi, qlo, qlo2;
  {
    const float* qp =
        query + (size_t)(n * LQ + (qtile << 4) + r16) * DM + h * DH + (g << 3);
    float qf[8];
    *(float4*)&qf[0] = *(const float4*)qp;
    *(float4*)&qf[4] = *(const float4*)(qp + 4);
    ushort uh[8], ul[8], ul2[8];
    #pragma unroll
    for (int j = 0; j < 8; ++j) {
      const float x = qf[j];
      const ushort h1 = bf16rn(x);
      const float r1 = x - bf16tof(h1);
      const ushort h2 = bf16rn(r1);
      const float r2 = r1 - bf16tof(h2);
      uh[j] = h1; ul[j] = h2; ul2[j] = bf16rn(r2);
    }
    qhi = (bf16x8){(short)uh[0], (short)uh[1], (short)uh[2], (short)uh[3],
                   (short)uh[4], (short)uh[5], (short)uh[6], (short)uh[7]};
    qlo = (bf16x8){(short)ul[0], (short)ul[1], (short)ul[2], (short)ul[3],
                   (short)ul[4], (short)ul[5], (short)ul[6], (short)ul[7]};
    qlo2 = (bf16x8){(short)ul2[0], (short)ul2[1], (short)ul2[2], (short)ul2[3],
                    (short)ul2[4], (short)ul2[5], (short)ul2[6], (short)ul2[7]};
  }

  // element-level top-4 state (sorted desc, lexicographic)
  float v0 = -INFINITY, v1 = -INFINITY, v2 = -INFINITY, v3 = -INFINITY;
  int i0 = 0, i1 = 0, i2 = 0, i3 = 0;

  // staging mapping: thread -> (srow = tid>>2, s = tid&3); corrected swizzle
  const int srow = tid >> 2, s = tid & 3;
  const int wslot = (s ^ ((srow >> 1) & 3)) << 3;
  const int rslot = (g ^ ((r16 >> 1) & 3)) << 3;  // (row>>1)&3 == (r16>>1)&3
  const ushort* psbase =
      PRESPLIT ? vs + ((((size_t)((n * NL + l) * NH + h)) << 10)) * 32 : nullptr;
  const float* vbase = value + (size_t)(n * LIN + l * HWsp) * DM + h * DH;

  for (int c = c0; c < c1; ++c) {
    if (PRESPLIT) {
      const size_t off = ((size_t)((c << 6) + srow)) * 32 + (s << 3);
      *(bf16x8*)&hiL[srow][wslot] = *(const bf16x8*)(psbase + off);
      *(bf16x8*)&loL[srow][wslot] = *(const bf16x8*)(psbase + PSTRIDE + off);
      *(bf16x8*)&lo2L[srow][wslot] = *(const bf16x8*)(psbase + 2 * PSTRIDE + off);
    } else {
      const float* vp = vbase + (size_t)((c << 6) + srow) * DM + (s << 3);
      float xf[8];
      *(float4*)&xf[0] = *(const float4*)vp;
      *(float4*)&xf[4] = *(const float4*)(vp + 4);
      ushort uh[8], ul[8], ul2[8];
      #pragma unroll
      for (int j = 0; j < 8; ++j) {
        const float x = xf[j];
        const ushort h1 = bf16rn(x);
        const float r1 = x - bf16tof(h1);
        const ushort h2 = bf16rn(r1);
        const float r2 = r1 - bf16tof(h2);
        uh[j] = h1; ul[j] = h2; ul2[j] = bf16rn(r2);
      }
      *(bf16x8*)&hiL[srow][wslot] =
          (bf16x8){(short)uh[0], (short)uh[1], (short)uh[2], (short)uh[3],
                   (short)uh[4], (short)uh[5], (short)uh[6], (short)uh[7]};
      *(bf16x8*)&loL[srow][wslot] =
          (bf16x8){(short)ul[0], (short)ul[1], (short)ul[2], (short)ul[3],
                   (short)ul[4], (short)ul[5], (short)ul[6], (short)ul[7]};
      *(bf16x8*)&lo2L[srow][wslot] =
          (bf16x8){(short)ul2[0], (short)ul2[1], (short)ul2[2], (short)ul2[3],
                   (short)ul2[4], (short)ul2[5], (short)ul2[6], (short)ul2[7]};
    }
    __syncthreads();

    #pragma unroll
    for (int t = 0; t < 4; ++t) {
      const int row = (t << 4) + r16;
      const bf16x8 ahi = *(const bf16x8*)&hiL[row][rslot];
      const bf16x8 alo = *(const bf16x8*)&loL[row][rslot];
      const bf16x8 alo2 = *(const bf16x8*)&lo2L[row][rslot];
      f32x4 acc = {0.f, 0.f, 0.f, 0.f};
      // smallest-first accumulation (validated R5-R12 ordering)
      acc = __builtin_amdgcn_mfma_f32_16x16x32_bf16(alo2, qhi, acc, 0, 0, 0);
      acc = __builtin_amdgcn_mfma_f32_16x16x32_bf16(ahi, qlo2, acc, 0, 0, 0);
      acc = __builtin_amdgcn_mfma_f32_16x16x32_bf16(alo, qlo, acc, 0, 0, 0);
      acc = __builtin_amdgcn_mfma_f32_16x16x32_bf16(alo, qhi, acc, 0, 0, 0);
      acc = __builtin_amdgcn_mfma_f32_16x16x32_bf16(ahi, qlo, acc, 0, 0, 0);
      acc = __builtin_amdgcn_mfma_f32_16x16x32_bf16(ahi, qhi, acc, 0, 0, 0);
      const int kb = (c << 6) + (t << 4) + (g << 2);
      INSERT4(acc[0], kb + 0);
      INSERT4(acc[1], kb + 1);
      INSERT4(acc[2], kb + 2);
      INSERT4(acc[3], kb + 3);
    }
    __syncthreads();
  }

  // ---- merge the 4 row-groups of this q-column (lanes 16/32) ----
  #pragma unroll
  for (int m = 16; m < 64; m <<= 1) {
    const float b0 = __shfl_xor(v0, m);
    const float b1 = __shfl_xor(v1, m);
    const float b2 = __shfl_xor(v2, m);
    const float b3 = __shfl_xor(v3, m);
    const int j0 = __shfl_xor(i0, m);
    const int j1 = __shfl_xor(i1, m);
    const int j2 = __shfl_xor(i2, m);
    const int j3 = __shfl_xor(i3, m);
    LMAX(v0, i0, b3, j3);
    LMAX(v1, i1, b2, j2);
    LMAX(v2, i2, b1, j1);
    LMAX(v3, i3, b0, j0);
    CEX(v0, i0, v2, i2);
    CEX(v1, i1, v3, i3);
    CEX(v0, i0, v1, i1);
    CEX(v2, i2, v3, i3);
  }

  if (L < 16) {
    const int q = (qtile << 4) + L;
    const size_t gi = (((size_t)nh * NL + l) << 10) + q;
    if (SPLIT == 2) {
      pval[gi * 2 + half] = make_float4(v0, v1, v2, v3);
      pidx[gi * 2 + half] = make_int4(i0, i1, i2, i3);
    } else {
      ((int4*)idx_out)[gi] = make_int4(i0, i1, i2, i3);
    }
  }
}

// ---------------------------------------------------------------------------
// Kernel 1b: merge the two k-half partial top-4 lists per group AND write the
// loc output directly (loc is a pure function of the final idx4).
// ---------------------------------------------------------------------------
__global__ __launch_bounds__(256) void merge_topk_loc_kernel(
    const float4* __restrict__ pval, const int4* __restrict__ pidx,
    int* __restrict__ idx_out, float* __restrict__ loc) {
  const int t = blockIdx.x * 256 + threadIdx.x;  // < NGRP
  const float4 av = pval[t * 2 + 0];
  const int4 ai = pidx[t * 2 + 0];
  const float4 bv = pval[t * 2 + 1];
  const int4 bi = pidx[t * 2 + 1];
  float w0 = av.x, w1 = av.y, w2 = av.z, w3 = av.w;
  int m0 = ai.x, m1 = ai.y, m2 = ai.z, m3 = ai.w;
  LMAX(w0, m0, bv.w, bi.w);
  LMAX(w1, m1, bv.z, bi.z);
  LMAX(w2, m2, bv.y, bi.y);
  LMAX(w3, m3, bv.x, bi.x);
  CEX(w0, m0, w2, m2);
  CEX(w1, m1, w3, m3);
  CEX(w0, m0, w1, m1);
  CEX(w2, m2, w3, m3);
  ((int4*)idx_out)[t] = make_int4(m0, m1, m2, m3);

  // decode group: gi = ((n*8+h)*4+l)*1024 + q
  const int q = t & 1023, l = (t >> 10) & 3, h = (t >> 12) & 7, n = t >> 15;
  // loc float2 base: (((n*1024+q)*8+h)*4+l)*36
  const size_t base2 =
      (size_t)((((((n << 10) + q) << 3) + h) << 2) + l) * 36;
  float4* lp4 = (float4*)(loc + base2 * 2);  // 288B per thread, 16B-aligned
  const int idxs[4] = {m0, m1, m2, m3};
  #pragma unroll
  for (int dd = 0; dd < 9; ++dd) {
    const int delta = (dd / 3 - 1) * 32 + (dd % 3) - 1;
    float vv[8];
    #pragma unroll
    for (int p = 0; p < 4; ++p) {
      int res = idxs[p] + delta;
      res = min(max(res, 0), 961);
      vv[p * 2] = (float)(res >> 5) * 0.03125f;
      vv[p * 2 + 1] = (float)(res & 31) * 0.03125f;
    }
    lp4[dd * 2] = make_float4(vv[0], vv[1], vv[2], vv[3]);
    lp4[dd * 2 + 1] = make_float4(vv[4], vv[5], vv[6], vv[7]);
  }
}

// ---------------------------------------------------------------------------
// Kernel 2 (tier-3 fallback only): standalone loc from idx_buf.
// ---------------------------------------------------------------------------
__global__ __launch_bounds__(256) void loc_kernel(const int* __restrict__ idx_buf,
                                                  float* __restrict__ loc) {
  const int t = blockIdx.x * 256 + threadIdx.x;  // < 2359296
  const int k = t % 36;
  int rest = t / 36;
  const int l = rest & 3; rest >>= 2;
  const int h = rest & 7; rest >>= 3;
  const int q = rest & 1023;
  const int n = rest >> 10;
  const int p = k & 3, dd = k >> 2;  // delta-major: k = dd*4 + p
  const int idx = idx_buf[(((((n << 3) + h) * NL + l) << 10) + q) * 4 + p];
  const int delta = ((dd / 3) - 1) * 32 + (dd % 3) - 1;
  int res = idx + delta;
  res = min(max(res, 0), 961);
  const int W = res >> 5, H = res & 31;
  ((float2*)loc)[t] = make_float2((float)W * 0.03125f, (float)H * 0.03125f);
}

// ---------------------------------------------------------------------------
// Kernel 3: gather+average, wave-per-(n,q,h,l) (R7-R12-validated).
// ---------------------------------------------------------------------------
__global__ __launch_bounds__(256) void gather_kernel(
    const float* __restrict__ value, const int* __restrict__ idx_buf,
    float* __restrict__ acc_out) {
  __shared__ float4 red[NL][8];
  const int bh = blockIdx.x;  // (n*1024+q)*8 + h
  const int h = bh & 7;
  const int nq = bh >> 3;
  const int n = nq >> 10, q = nq & 1023;
  const int tid = threadIdx.x;
  const int l = tid >> 6;  // wave = level
  const int L = tid & 63;
  const int cp = L >> 3, d4 = L & 7;

  const int4 id4 =
      ((const int4*)idx_buf)[((((size_t)((n << 3) + h)) * NL + l) << 10) + q];
  const float4* vb4 =
      (const float4*)(value + (size_t)(n * LIN + l * HWsp) * DM + h * DH) + d4;

  float4 a = make_float4(0.f, 0.f, 0.f, 0.f);
  #pragma unroll
  for (int p = 0; p < 4; ++p) {
    const int idx = (p == 0) ? id4.x : (p == 1) ? id4.y : (p == 2) ? id4.z : id4.w;
    const int H0 = idx & 31, W0 = idx >> 5;
    if (H0 >= 2 && H0 <= 30 && W0 >= 2 && W0 <= 28) {
      const int idxT = (H0 << 5) + W0;
      const int c0i = cp << 1;
      const int ax0 = c0i & 3, ay = c0i >> 2;
      const int r0 = idxT + (ax0 - 2) * 32 + (ay - 2);
      const float wy = (ay == 1 || ay == 2) ? 2.f : 1.f;
      const float f0 = ((ax0 == 2) ? 2.f : 1.f) * wy;
      const float f1 = ((ax0 + 1 == 1) ? 2.f : 1.f) * wy;
      const float4 va = vb4[(size_t)r0 * 64];
      const float4 vbb = vb4[(size_t)(r0 + 32) * 64];
      a.x += f0 * va.x + f1 * vbb.x;
      a.y += f0 * va.y + f1 * vbb.y;
      a.z += f0 * va.z + f1 * vbb.z;
      a.w += f0 * va.w + f1 * vbb.w;
    } else {
      #pragma unroll
      for (int it = 0; it < 5; ++it) {
        const int u = cp + (it << 3);
        const int cell = u >> 2, corner = u & 3;
        const int dy = (cell >= 3) + (cell >= 6) - 1;
        const int dx = cell - (dy + 1) * 3 - 1;
        int res = idx + dy * 32 + dx;
        res = min(max(res, 0), 961);
        const int W = res >> 5, H = res & 31;
        const int cw = corner & 1, ch = corner >> 1;
        const bool ok = (u < 36) && (W >= cw) && (H >= ch);
        const int row = ok ? (((H - ch) << 5) + (W - cw)) : 0;
        const float wgt = ok ? 1.f : 0.f;
        const float4 v = vb4[(size_t)row * 64];
        a.x += wgt * v.x;
        a.y += wgt * v.y;
        a.z += wgt * v.z;
        a.w += wgt * v.w;
      }
    }
  }

  #pragma unroll
  for (int m = 8; m < 64; m <<= 1) {
    a.x += __shfl_xor(a.x, m);
    a.y += __shfl_xor(a.y, m);
    a.z += __shfl_xor(a.z, m);
    a.w += __shfl_xor(a.w, m);
  }
  if (L < 8) red[l][L] = a;
  __syncthreads();
  if (tid < 8) {
    const float4 s0 = red[0][tid], s1 = red[1][tid], s2 = red[2][tid],
                 s3 = red[3][tid];
    float4 o;
    o.x = (s0.x + s1.x + s2.x + s3.x) * (1.0f / 576.0f);
    o.y = (s0.y + s1.y + s2.y + s3.y) * (1.0f / 576.0f);
    o.z = (s0.z + s1.z + s2.z + s3.z) * (1.0f / 576.0f);
    o.w = (s0.w + s1.w + s2.w + s3.w) * (1.0f / 576.0f);
    ((float4*)(acc_out + (size_t)nq * DM + h * DH))[tid] = o;
  }
}

// ---------------------------------------------------------------------------
// Kernel 4: out = acc @ W^T + b.  256 blocks x 256 threads, 8 q-rows/block.
// ---------------------------------------------------------------------------
__global__ __launch_bounds__(256) void proj_kernel(
    const float* __restrict__ acc_in, const float* __restrict__ W,
    const float* __restrict__ bias, float* __restrict__ out) {
  __shared__ float la[8][256];
  const int qb = blockIdx.x << 3;
  const int tid = threadIdx.x;
  for (int i = tid; i < 8 * 256; i += 256)
    la[i >> 8][i & 255] = acc_in[((size_t)qb << 8) + i];
  __syncthreads();
  const float* wrow = W + (size_t)tid * 256;
  float s0 = 0.f, s1 = 0.f, s2 = 0.f, s3 = 0.f, s4 = 0.f, s5 = 0.f, s6 = 0.f, s7 = 0.f;
  for (int c0 = 0; c0 < 256; c0 += 4) {
    const float4 wv = *(const float4*)(wrow + c0);
    #define PROJ_STEP(qi, sreg)                                   \
      {                                                           \
        const float4 av = *(const float4*)&la[qi][c0];            \
        sreg = fmaf(wv.x, av.x, sreg);                            \
        sreg = fmaf(wv.y, av.y, sreg);                            \
        sreg = fmaf(wv.z, av.z, sreg);                            \
        sreg = fmaf(wv.w, av.w, sreg);                            \
      }
    PROJ_STEP(0, s0) PROJ_STEP(1, s1) PROJ_STEP(2, s2) PROJ_STEP(3, s3)
    PROJ_STEP(4, s4) PROJ_STEP(5, s5) PROJ_STEP(6, s6) PROJ_STEP(7, s7)
    #undef PROJ_STEP
  }
  const float bj = bias[tid];
  out[(size_t)(qb + 0) * 256 + tid] = s0 + bj;
  out[(size_t)(qb + 1) * 256 + tid] = s1 + bj;
  out[(size_t)(qb + 2) * 256 + tid] = s2 + bj;
  out[(size_t)(qb + 3) * 256 + tid] = s3 + bj;
  out[(size_t)(qb + 4) * 256 + tid] = s4 + bj;
  out[(size_t)(qb + 5) * 256 + tid] = s5 + bj;
  out[(size_t)(qb + 6) * 256 + tid] = s6 + bj;
  out[(size_t)(qb + 7) * 256 + tid] = s7 + bj;
}

// ---------------------------------------------------------------------------
extern "C" void kernel_launch(void* const* d_in, const int* in_sizes, int n_in,
                              void* d_out, int out_size, void* d_ws, size_t ws_size,
                              hipStream_t stream) {
  (void)in_sizes; (void)n_in; (void)out_size;
  const float* query = (const float*)d_in[0];
  const float* value = (const float*)d_in[2];
  const float* opw = (const float*)d_in[5];
  const float* opb = (const float*)d_in[6];

  float* out = (float*)d_out;               // [2,1024,256]
  float* loc = out + (size_t)BB * LQ * DM;  // [2,1024,8,4,36,2]

  const size_t SPLITB = 3 * PSTRIDE * sizeof(ushort);        // 12.58 MB
  const size_t PARTB = (size_t)NGRP * 2 * 16;                // 2 MB each
  const size_t IDXB = (size_t)NGRP * 4 * sizeof(int);        // 1 MB
  const size_t ACCB = (size_t)BB * LQ * DM * sizeof(float);  // 2 MB

  if (ws_size >= SPLITB + 2 * PARTB + IDXB + ACCB) {
    // tier 1 (measured best): presplit + k-split x2; merge+loc fused
    ushort* vsb = (ushort*)d_ws;
    float4* pval = (float4*)((char*)d_ws + SPLITB);
    int4* pidx = (int4*)((char*)d_ws + SPLITB + PARTB);
    int* idx_buf = (int*)((char*)d_ws + SPLITB + 2 * PARTB);
    float* acc_buf = (float*)((char*)d_ws + SPLITB + 2 * PARTB + IDXB);

    vsplit_kernel<<<dim3(1024), 256, 0, stream>>>(value, vsb);
    corr_topk_kernel<2, 1><<<dim3(32, NL, BB * NH), 256, 0, stream>>>(
        query, value, vsb, idx_buf, pval, pidx);
    merge_topk_loc_kernel<<<dim3(NGRP / 256), 256, 0, stream>>>(pval, pidx,
                                                                idx_buf, loc);
    gather_kernel<<<dim3(BB * LQ * NH), 256, 0, stream>>>(value, idx_buf, acc_buf);
    proj_kernel<<<dim3(BB * LQ / 8), 256, 0, stream>>>(acc_buf, opw, opb, out);
  } else if (ws_size >= 2 * PARTB + IDXB + ACCB) {
    // tier 2: in-kernel conversion + k-split x2; merge+loc fused
    float4* pval = (float4*)d_ws;
    int4* pidx = (int4*)((char*)d_ws + PARTB);
    int* idx_buf = (int*)((char*)d_ws + 2 * PARTB);
    float* acc_buf = (float*)((char*)d_ws + 2 * PARTB + IDXB);

    corr_topk_kernel<2, 0><<<dim3(32, NL, BB * NH), 256, 0, stream>>>(
        query, value, (const ushort*)nullptr, idx_buf, pval, pidx);
    merge_topk_loc_kernel<<<dim3(NGRP / 256), 256, 0, stream>>>(pval, pidx,
                                                                idx_buf, loc);
    gather_kernel<<<dim3(BB * LQ * NH), 256, 0, stream>>>(value, idx_buf, acc_buf);
    proj_kernel<<<dim3(BB * LQ / 8), 256, 0, stream>>>(acc_buf, opw, opb, out);
  } else {
    // tier 3: minimal workspace, single-pass + standalone loc
    int* idx_buf = (int*)d_ws;
    float* acc_buf = (float*)((char*)d_ws + IDXB);

    corr_topk_kernel<1, 0><<<dim3(16, NL, BB * NH), 256, 0, stream>>>(
        query, value, (const ushort*)nullptr, idx_buf, (float4*)nullptr,
        (int4*)nullptr);
    loc_kernel<<<dim3((BB * LQ * NH * NL * K9) / 256), 256, 0, stream>>>(idx_buf, loc);
    gather_kernel<<<dim3(BB * LQ * NH), 256, 0, stream>>>(value, idx_buf, acc_buf);
    proj_kernel<<<dim3(BB * LQ / 8), 256, 0, stream>>>(acc_buf, opw, opb, out);
  }
}